// Round 5
// baseline (1708.796 us; speedup 1.0000x reference)
//
#include <hip/hip_runtime.h>

#define N_DATA     131072
#define D_VECTOR   128
#define N_SUB      8
#define D_SUB      16
#define N_CLUSTERS 256
#define N_CODEBOOKS 64

typedef float v2f __attribute__((ext_vector_type(2)));

// ws layout in 4-byte words (~2.5 MB base; +8 MiB optional cbT if ws permits).
// xg[s][dst][16] (permuted-gathered x, 64 MiB) lives in d_out until decode
// overwrites it.
#define WS_LABELS 0
#define WS_PERM   (N_DATA)
#define WS_CNT    (2*N_DATA)
#define WS_CURSOR (2*N_DATA + 64)
#define WS_OFF    (2*N_DATA + 128)
#define WS_CNORM  (2*N_DATA + 256)                  // 512 rows x 256 k, numpy-order fp32
#define WS_CNSEL  (WS_CNORM + N_CODEBOOKS*N_SUB*N_CLUSTERS)
#define WS_CODES  (WS_CNSEL + 64)                   // 131072*8 bytes = 262144 words
#define WS_CBT    (WS_CODES + 262144)               // optional: pair-interleaved codebook
#define CBT_WORDS (N_CODEBOOKS*N_SUB*N_CLUSTERS*D_SUB)   // 2,097,152 words = 8 MiB

// ---------------------------------------------------------------- precompute
// cnorm = np.sum(cb*cb, axis=2) (sequential d, separate mul/add). If cbT is
// non-null, also emit the pair-interleaved codebook
//   cbT[row][k>>1][d][k&1] = cb[row][d][k]       (row = l*8+s)
// giving 32 contiguous floats per k-pair: encode streams it with sequential
// s_load_dwordx16; decode reads a point's 16 d's at stride 2 (2 lines).
__global__ __launch_bounds__(256) void pq_precompute(
    const float* __restrict__ cb, const float* __restrict__ sel,
    float* __restrict__ cnorm_cb, float* __restrict__ cnorm_sel,
    float* __restrict__ cbT, int* __restrict__ cnt)
{
    int row = blockIdx.x;                 // 0..511 = l*8+s
    int k   = threadIdx.x;                // 0..255
    const float* p = cb + (size_t)row * (D_SUB * N_CLUSTERS) + k;
    float* ct = cbT ? cbT + ((size_t)row << 12) + ((size_t)(k >> 1) << 5) + (k & 1) : (float*)0;
    float sum = 0.f;
#pragma unroll
    for (int d = 0; d < D_SUB; d++) {
        float v = p[(size_t)d * N_CLUSTERS];
        if (ct) ct[d << 1] = v;
        sum = __fadd_rn(sum, __fmul_rn(v, v));
    }
    int idx = row * 256 + k;
    cnorm_cb[idx] = sum;
    if (idx < N_CODEBOOKS) {
        float s2 = 0.f;
        for (int d = 0; d < D_VECTOR; d++) {
            float v = sel[d * N_CODEBOOKS + idx];
            s2 = __fadd_rn(s2, __fmul_rn(v, v));
        }
        cnorm_sel[idx] = s2;
        cnt[idx] = 0;
    }
}

// ---------------------------------------------------------------- stage 1: labels
__global__ __launch_bounds__(256, 4) void pq_labels2(
    const float* __restrict__ x, const float* __restrict__ sel,
    const float* __restrict__ cnorm_sel,
    int* __restrict__ labels, int* __restrict__ cnt)
{
    __shared__ int hist[N_CODEBOOKS];
    int tid = threadIdx.x;
    if (tid < N_CODEBOOKS) hist[tid] = 0;
    __syncthreads();

    int n = blockIdx.x * 256 + tid;

    v2f acc[32];
#pragma unroll
    for (int lp = 0; lp < 32; lp++) acc[lp] = (v2f){0.f, 0.f};

    float xn = 0.f;
    for (int d = 0; d < D_VECTOR; d++) {
        float xv = x[(size_t)d * N_DATA + n];        // coalesced
        xn = __fadd_rn(xn, __fmul_rn(xv, xv));       // sequential d: numpy-exact
        v2f xv2 = (v2f){xv, xv};
        const v2f* sp = (const v2f*)(sel + d * N_CODEBOOKS);  // uniform
#pragma unroll
        for (int lp = 0; lp < 32; lp++)
            acc[lp] = __builtin_elementwise_fma(xv2, sp[lp], acc[lp]);  // v_pk_fma_f32
    }

    float best = 1e30f;
    int   bl = 0;
#pragma unroll
    for (int lp = 0; lp < 32; lp++) {
        float dx = __fadd_rn(__fsub_rn(xn, __fmul_rn(2.0f, acc[lp].x)), cnorm_sel[2*lp]);
        float dy = __fadd_rn(__fsub_rn(xn, __fmul_rn(2.0f, acc[lp].y)), cnorm_sel[2*lp + 1]);
        if (dx < best) { best = dx; bl = 2*lp; }
        if (dy < best) { best = dy; bl = 2*lp + 1; }
    }
    labels[n] = bl;
    atomicAdd(&hist[bl], 1);
    __syncthreads();
    if (tid < N_CODEBOOKS) atomicAdd(&cnt[tid], hist[tid]);
}

// ---------------------------------------------------------------- scan (1 wave)
__global__ void pq_scan(const int* __restrict__ cnt, int* __restrict__ off, int* __restrict__ cursor)
{
    int tid = threadIdx.x;
    int v = cnt[tid];
    int inc = v;
#pragma unroll
    for (int sft = 1; sft < 64; sft <<= 1) {
        int o = __shfl_up(inc, sft, 64);
        if (tid >= sft) inc += o;
    }
    int exc = inc - v;
    off[tid] = exc;
    cursor[tid] = exc;
    if (tid == 63) off[64] = inc;
}

// ---------------------------------------------------------------- counting-sort scatter + permute-gather
__global__ __launch_bounds__(256) void pq_scatter(
    const float* __restrict__ x, const int* __restrict__ labels,
    int* __restrict__ cursor, unsigned int* __restrict__ perm,
    float* __restrict__ xg)
{
    __shared__ int lcnt[N_CODEBOOKS];
    __shared__ int lbase[N_CODEBOOKS];
    int tid = threadIdx.x;
    if (tid < N_CODEBOOKS) lcnt[tid] = 0;
    __syncthreads();
    int base = blockIdx.x * 1024;
    int lv[4], slot[4];
#pragma unroll
    for (int i = 0; i < 4; i++) {
        int n = base + i * 256 + tid;
        int l = labels[n];
        lv[i] = l;
        slot[i] = atomicAdd(&lcnt[l], 1);
    }
    __syncthreads();
    if (tid < N_CODEBOOKS) lbase[tid] = atomicAdd(&cursor[tid], lcnt[tid]);
    __syncthreads();
#pragma unroll
    for (int i = 0; i < 4; i++) {
        int n = base + i * 256 + tid;
        int dst = lbase[lv[i]] + slot[i];
        perm[dst] = ((unsigned)n << 6) | (unsigned)lv[i];
#pragma unroll
        for (int s = 0; s < N_SUB; s++) {
            float v[D_SUB];
#pragma unroll
            for (int d = 0; d < D_SUB; d++)
                v[d] = x[(size_t)(s * D_SUB + d) * N_DATA + n];   // coalesced
            float4* o = (float4*)(xg + (((size_t)s * N_DATA + (size_t)dst) << 4));
            o[0] = make_float4(v[0],  v[1],  v[2],  v[3]);
            o[1] = make_float4(v[4],  v[5],  v[6],  v[7]);
            o[2] = make_float4(v[8],  v[9],  v[10], v[11]);
            o[3] = make_float4(v[12], v[13], v[14], v[15]);
        }
    }
}

// ---------------------------------------------------------------- stage 2: PQ encode v9 (big-ws)
// Lane = TWO points (pos, pos+64), perm-sorted; x from xg fully coalesced.
// Codebook: pair-interleaved cbT row streamed via wave-uniform scalar loads,
// 32 contiguous floats per k-pair, MANUALLY double-buffered (load kkp+1's
// block into the alternate SGPR set before computing kkp) so the ~200cy L2
// s_load latency hides under the ~2x270cy of per-kkp math. Boundary waves
// use the ballot multipass. Arithmetic per (point,k) unchanged: sequential-d
// separate mul/add (contract off), dist = (xn - 2*acc) + cn; per-component
// argmin chains (even/odd k) ascending kkp strict <, merged with the exact
// lower-k tie rule -> numpy first-occurrence. Distances NaN-free.
__global__ __launch_bounds__(256, 6) void pq_encode10(
    const float* __restrict__ xg, const float* __restrict__ cbT,
    const float* __restrict__ cnorm_cb, const unsigned int* __restrict__ perm,
    unsigned char* __restrict__ codes)
{
    int tid  = threadIdx.x;
    int lane = tid & 63;
    int w    = tid >> 6;
    int s    = blockIdx.x & 7;
    int base = (int)(blockIdx.x >> 3) * 512 + w * 128;
    int pos0 = base + lane;
    int pos1 = pos0 + 64;

    unsigned pk0 = perm[pos0], pk1 = perm[pos1];
    int n0 = (int)(pk0 >> 6), l0 = (int)(pk0 & 63u);
    int n1 = (int)(pk1 >> 6), l1 = (int)(pk1 & 63u);

    const float4* xp0 = (const float4*)(xg + (((size_t)s * N_DATA + (size_t)pos0) << 4));
    const float4* xp1 = (const float4*)(xg + (((size_t)s * N_DATA + (size_t)pos1) << 4));
    float4 a0 = xp0[0], a1 = xp0[1], a2 = xp0[2], a3 = xp0[3];
    float4 b0 = xp1[0], b1 = xp1[1], b2 = xp1[2], b3 = xp1[3];
    float xsA[D_SUB] = { a0.x,a0.y,a0.z,a0.w, a1.x,a1.y,a1.z,a1.w,
                         a2.x,a2.y,a2.z,a2.w, a3.x,a3.y,a3.z,a3.w };
    float xsB[D_SUB] = { b0.x,b0.y,b0.z,b0.w, b1.x,b1.y,b1.z,b1.w,
                         b2.x,b2.y,b2.z,b2.w, b3.x,b3.y,b3.z,b3.w };

    // xnorm: numpy strided reduction (sequential d, separate mul/add)
    float xn0 = 0.f, xn1 = 0.f;
#pragma unroll
    for (int d = 0; d < D_SUB; d++) {
        xn0 = __fadd_rn(xn0, __fmul_rn(xsA[d], xsA[d]));
        xn1 = __fadd_rn(xn1, __fmul_rn(xsB[d], xsB[d]));
    }

    v2f xs20[D_SUB], xs21[D_SUB];
#pragma unroll
    for (int d = 0; d < D_SUB; d++) { xs20[d] = (v2f){xsA[d], xsA[d]}; xs21[d] = (v2f){xsB[d], xsB[d]}; }
    const v2f xnv0 = (v2f){xn0, xn0}, xnv1 = (v2f){xn1, xn1};
    const v2f twov = (v2f){2.f, 2.f};

    bool d0 = false, d1 = false;
    int bk0 = 0, bk1 = 0;

    while (true) {
        unsigned long long todo = __ballot(!d0 || !d1);
        if (!todo) break;
        int src  = (int)(__ffsll((long long)todo) - 1);
        int lsel = (!d0) ? l0 : l1;                        // valid pending label on src
        int lcur = __builtin_amdgcn_readlane(lsel, src);   // uniform label for this pass

        const v2f* cbp = (const v2f*)(cbT      + ((size_t)(lcur * N_SUB + s) << 12));
        const v2f* cnp = (const v2f*)(cnorm_cb + ((size_t)(lcur * N_SUB + s) << 8));

        float b0x = 1e30f, b0y = 1e30f, b1x = 1e30f, b1y = 1e30f;
        int   k0x = 0, k0y = 0, k1x = 0, k1y = 0;
        {
#pragma clang fp contract(off)
            v2f cA[16], cB[16], cnA, cnB;
            cnA = cnp[0];
#pragma unroll
            for (int j = 0; j < 16; j++) cA[j] = cbp[j];

#define PQ_COMP(CREG, CNREG, KKP)                                              \
            do {                                                               \
                v2f q0 = (v2f){0.f, 0.f}, q1 = (v2f){0.f, 0.f};                \
                _Pragma("unroll")                                              \
                for (int d = 0; d < D_SUB; d++) {                              \
                    v2f c = CREG[d];                                           \
                    q0 = q0 + xs20[d] * c;    /* pk mul + pk add, exact */     \
                    q1 = q1 + xs21[d] * c;                                     \
                }                                                              \
                v2f e0 = (xnv0 - twov * q0) + CNREG;                           \
                v2f e1 = (xnv1 - twov * q1) + CNREG;                           \
                if (e0.x < b0x) { b0x = e0.x; k0x = (KKP); }                   \
                if (e0.y < b0y) { b0y = e0.y; k0y = (KKP); }                   \
                if (e1.x < b1x) { b1x = e1.x; k1x = (KKP); }                   \
                if (e1.y < b1y) { b1y = e1.y; k1y = (KKP); }                   \
            } while (0)

#pragma clang loop unroll(disable)
            for (int kk = 0; kk < N_CLUSTERS / 2; kk += 2) {
                // prefetch kk+1 into B, compute kk from A
                cnB = cnp[kk + 1];
#pragma unroll
                for (int j = 0; j < 16; j++) cB[j] = cbp[(kk + 1) * 16 + j];
                PQ_COMP(cA, cnA, kk);
                // prefetch kk+2 into A, compute kk+1 from B
                if (kk + 2 < N_CLUSTERS / 2) {
                    cnA = cnp[kk + 2];
#pragma unroll
                    for (int j = 0; j < 16; j++) cA[j] = cbp[(kk + 2) * 16 + j];
                }
                PQ_COMP(cB, cnB, kk + 1);
            }
#undef PQ_COMP
        }
        // merge even/odd chains: strictly-better or equal-with-lower-k picks odd
        int m0 = 2 * k0x;
        { int ko = 2 * k0y + 1; if (b0y < b0x || (b0y == b0x && ko < m0)) m0 = ko; }
        int m1 = 2 * k1x;
        { int ko = 2 * k1y + 1; if (b1y < b1x || (b1y == b1x && ko < m1)) m1 = ko; }

        if (!d0 && l0 == lcur) { bk0 = m0; d0 = true; }
        if (!d1 && l1 == lcur) { bk1 = m1; d1 = true; }
    }
    codes[((size_t)n0 << 3) | s] = (unsigned char)bk0;
    codes[((size_t)n1 << 3) | s] = (unsigned char)bk1;
}

// ---------------------------------------------------------------- stage 2 fallback (small-ws): v8 encode
__global__ __launch_bounds__(256, 8) void pq_encode9(
    const float* __restrict__ xg, const float* __restrict__ cb,
    const float* __restrict__ cnorm_cb, const unsigned int* __restrict__ perm,
    unsigned char* __restrict__ codes)
{
    int tid = threadIdx.x;
    int s   = blockIdx.x & 7;
    int pos = (int)(blockIdx.x >> 3) * 256 + tid;
    unsigned pk = perm[pos];
    int n = (int)(pk >> 6);
    int l = (int)(pk & 63u);

    const float4* xp = (const float4*)(xg + (((size_t)s * N_DATA + (size_t)pos) << 4));
    float4 x0 = xp[0], x1 = xp[1], x2 = xp[2], x3 = xp[3];
    float xs[D_SUB] = { x0.x, x0.y, x0.z, x0.w, x1.x, x1.y, x1.z, x1.w,
                        x2.x, x2.y, x2.z, x2.w, x3.x, x3.y, x3.z, x3.w };

    float xn = 0.f;
#pragma unroll
    for (int d = 0; d < D_SUB; d++)
        xn = __fadd_rn(xn, __fmul_rn(xs[d], xs[d]));

    v2f xs2[D_SUB];
#pragma unroll
    for (int d = 0; d < D_SUB; d++) xs2[d] = (v2f){xs[d], xs[d]};
    const v2f xnv  = (v2f){xn, xn};
    const v2f twov = (v2f){2.f, 2.f};

    int bestk = 0;
    bool done = false;
    while (true) {
        unsigned long long todo = __ballot(!done);
        if (!todo) break;
        int src  = (int)(__ffsll((long long)todo) - 1);
        int lcur = __builtin_amdgcn_readlane(l, src);

        const float* cbs = cb       + ((size_t)(lcur * N_SUB + s) << 12);
        const float* cns = cnorm_cb + ((size_t)(lcur * N_SUB + s) << 8);

        float bx = 1e30f, by = 1e30f;
        int   kx = 0, ky = 0;
        {
#pragma clang fp contract(off)
#pragma unroll 2
            for (int kkp = 0; kkp < N_CLUSTERS / 2; kkp++) {
                v2f cn2 = *(const v2f*)(cns + (kkp << 1));
                v2f a = (v2f){0.f, 0.f};
#pragma unroll
                for (int d = 0; d < D_SUB; d++) {
                    v2f c = *(const v2f*)(cbs + (size_t)(d * N_CLUSTERS) + (kkp << 1));
                    a = a + xs2[d] * c;
                }
                v2f dd = (xnv - twov * a) + cn2;
                if (dd.x < bx) { bx = dd.x; kx = kkp; }
                if (dd.y < by) { by = dd.y; ky = kkp; }
            }
        }
        int bk = 2 * kx;
        { int kodd = 2 * ky + 1; if (by < bx || (by == bx && kodd < bk)) bk = kodd; }

        if (!done && l == lcur) { bestk = bk; done = true; }
    }
    codes[((size_t)n << 3) | s] = (unsigned char)bestk;
}

// ---------------------------------------------------------------- decode (fast): 2 lines per (n,s), from cbT
__global__ __launch_bounds__(256) void pq_decode_fast(
    const float* __restrict__ cbT, const int* __restrict__ labels,
    const unsigned char* __restrict__ codes, float* __restrict__ out)
{
    int s = blockIdx.x & 7;
    int n = (blockIdx.x >> 3) * 256 + threadIdx.x;
    int l = labels[n];
    int k = codes[(size_t)n * N_SUB + s];
    const float* base = cbT + ((size_t)(l * N_SUB + s) << 12) + ((size_t)(k >> 1) << 5) + (k & 1);
    float v[D_SUB];
#pragma unroll
    for (int dd = 0; dd < D_SUB; dd++) v[dd] = base[dd << 1];
#pragma unroll
    for (int dd = 0; dd < D_SUB; dd++)
        out[(size_t)(s * D_SUB + dd) * N_DATA + n] = v[dd];   // coalesced
}

// ---------------------------------------------------------------- decode (fallback): strided column gather
__global__ __launch_bounds__(256) void pq_decode(
    const float* __restrict__ cb, const int* __restrict__ labels,
    const unsigned char* __restrict__ codes, float* __restrict__ out)
{
    int s = blockIdx.x & 7;
    int n = (blockIdx.x >> 3) * 256 + threadIdx.x;
    int l = labels[n];
    int k = codes[(size_t)n * N_SUB + s];
    const float* base = cb + ((size_t)(l * N_SUB + s) * D_SUB) * N_CLUSTERS + k;
#pragma unroll
    for (int dd = 0; dd < D_SUB; dd++)
        out[(size_t)(s * D_SUB + dd) * N_DATA + n] = base[(size_t)dd * N_CLUSTERS];
}

// ---------------------------------------------------------------- launcher
extern "C" void kernel_launch(void* const* d_in, const int* in_sizes, int n_in,
                              void* d_out, int out_size, void* d_ws, size_t ws_size,
                              hipStream_t stream)
{
    (void)in_sizes; (void)n_in; (void)out_size;
    const float* x   = (const float*)d_in[0];
    const float* cb  = (const float*)d_in[1];
    const float* sel = (const float*)d_in[2];
    float* out = (float*)d_out;

    int*   wsi    = (int*)d_ws;
    float* wsf    = (float*)d_ws;
    int*   labels = wsi + WS_LABELS;
    unsigned int* perm = (unsigned int*)(wsi + WS_PERM);
    int*   cnt    = wsi + WS_CNT;
    int*   cursor = wsi + WS_CURSOR;
    int*   off    = wsi + WS_OFF;
    float* cnorm  = wsf + WS_CNORM;
    float* cnsel  = wsf + WS_CNSEL;
    unsigned char* codes = (unsigned char*)(wsi + WS_CODES);

    // pair-interleaved codebook only if the workspace is big enough (~11 MiB)
    bool big = ws_size >= (size_t)(WS_CBT + CBT_WORDS) * 4u;
    float* cbT = big ? (wsf + WS_CBT) : (float*)nullptr;

    // permuted-gathered x (64 MiB) lives in d_out; decode overwrites it fully
    float* xg = out;

    hipLaunchKernelGGL(pq_precompute, dim3(512), dim3(256), 0, stream, cb, sel, cnorm, cnsel, cbT, cnt);
    hipLaunchKernelGGL(pq_labels2, dim3(N_DATA / 256), dim3(256), 0, stream, x, sel, cnsel, labels, cnt);
    hipLaunchKernelGGL(pq_scan, dim3(1), dim3(64), 0, stream, cnt, off, cursor);
    hipLaunchKernelGGL(pq_scatter, dim3(N_DATA / 1024), dim3(256), 0, stream, x, labels, cursor, perm, xg);
    if (big) {
        hipLaunchKernelGGL(pq_encode10, dim3((N_DATA / 512) * N_SUB), dim3(256), 0, stream,
                           xg, cbT, cnorm, perm, codes);
        hipLaunchKernelGGL(pq_decode_fast, dim3((N_DATA / 256) * N_SUB), dim3(256), 0, stream,
                           cbT, labels, codes, out);
    } else {
        hipLaunchKernelGGL(pq_encode9, dim3((N_DATA / 256) * N_SUB), dim3(256), 0, stream,
                           xg, cb, cnorm, perm, codes);
        hipLaunchKernelGGL(pq_decode, dim3((N_DATA / 256) * N_SUB), dim3(256), 0, stream,
                           cb, labels, codes, out);
    }
}

// Round 6
// 475.891 us; speedup vs baseline: 3.5907x; 3.5907x over previous
//
#include <hip/hip_runtime.h>

#define N_DATA     131072
#define D_VECTOR   128
#define N_SUB      8
#define D_SUB      16
#define N_CLUSTERS 256
#define N_CODEBOOKS 64

typedef float v2f __attribute__((ext_vector_type(2)));

// ws layout in 4-byte words (~2.5 MB base; +8 MiB optional cbT if ws permits).
// xg[s][dst][16] (permuted-gathered x, 64 MiB) lives in d_out until decode
// overwrites it.
#define WS_LABELS 0
#define WS_PERM   (N_DATA)
#define WS_CNT    (2*N_DATA)
#define WS_CURSOR (2*N_DATA + 64)
#define WS_OFF    (2*N_DATA + 128)
#define WS_CNORM  (2*N_DATA + 256)                  // 512 rows x 256 k, numpy-order fp32
#define WS_CNSEL  (WS_CNORM + N_CODEBOOKS*N_SUB*N_CLUSTERS)
#define WS_CODES  (WS_CNSEL + 64)                   // 131072*8 bytes = 262144 words
#define WS_CBT    (WS_CODES + 262144)               // optional: pair-interleaved codebook
#define CBT_WORDS (N_CODEBOOKS*N_SUB*N_CLUSTERS*D_SUB)   // 2,097,152 words = 8 MiB

// ---------------------------------------------------------------- precompute
// cnorm = np.sum(cb*cb, axis=2) (sequential d, separate mul/add). If cbT is
// non-null, also emit the pair-interleaved codebook
//   cbT[row][k>>1][d][k&1] = cb[row][d][k]       (row = l*8+s)
// giving 32 contiguous floats per k-pair: encode streams it with sequential
// s_load_dwordx16; decode reads a point's 16 d's at stride 2 (2 lines).
__global__ __launch_bounds__(256) void pq_precompute(
    const float* __restrict__ cb, const float* __restrict__ sel,
    float* __restrict__ cnorm_cb, float* __restrict__ cnorm_sel,
    float* __restrict__ cbT, int* __restrict__ cnt)
{
    int row = blockIdx.x;                 // 0..511 = l*8+s
    int k   = threadIdx.x;                // 0..255
    const float* p = cb + (size_t)row * (D_SUB * N_CLUSTERS) + k;
    float* ct = cbT ? cbT + ((size_t)row << 12) + ((size_t)(k >> 1) << 5) + (k & 1) : (float*)0;
    float sum = 0.f;
#pragma unroll
    for (int d = 0; d < D_SUB; d++) {
        float v = p[(size_t)d * N_CLUSTERS];
        if (ct) ct[d << 1] = v;
        sum = __fadd_rn(sum, __fmul_rn(v, v));
    }
    int idx = row * 256 + k;
    cnorm_cb[idx] = sum;
    if (idx < N_CODEBOOKS) {
        float s2 = 0.f;
        for (int d = 0; d < D_VECTOR; d++) {
            float v = sel[d * N_CODEBOOKS + idx];
            s2 = __fadd_rn(s2, __fmul_rn(v, v));
        }
        cnorm_sel[idx] = s2;
        cnt[idx] = 0;
    }
}

// ---------------------------------------------------------------- stage 1: labels
__global__ __launch_bounds__(256, 4) void pq_labels2(
    const float* __restrict__ x, const float* __restrict__ sel,
    const float* __restrict__ cnorm_sel,
    int* __restrict__ labels, int* __restrict__ cnt)
{
    __shared__ int hist[N_CODEBOOKS];
    int tid = threadIdx.x;
    if (tid < N_CODEBOOKS) hist[tid] = 0;
    __syncthreads();

    int n = blockIdx.x * 256 + tid;

    v2f acc[32];
#pragma unroll
    for (int lp = 0; lp < 32; lp++) acc[lp] = (v2f){0.f, 0.f};

    float xn = 0.f;
    for (int d = 0; d < D_VECTOR; d++) {
        float xv = x[(size_t)d * N_DATA + n];        // coalesced
        xn = __fadd_rn(xn, __fmul_rn(xv, xv));       // sequential d: numpy-exact
        v2f xv2 = (v2f){xv, xv};
        const v2f* sp = (const v2f*)(sel + d * N_CODEBOOKS);  // uniform
#pragma unroll
        for (int lp = 0; lp < 32; lp++)
            acc[lp] = __builtin_elementwise_fma(xv2, sp[lp], acc[lp]);  // v_pk_fma_f32
    }

    float best = 1e30f;
    int   bl = 0;
#pragma unroll
    for (int lp = 0; lp < 32; lp++) {
        float dx = __fadd_rn(__fsub_rn(xn, __fmul_rn(2.0f, acc[lp].x)), cnorm_sel[2*lp]);
        float dy = __fadd_rn(__fsub_rn(xn, __fmul_rn(2.0f, acc[lp].y)), cnorm_sel[2*lp + 1]);
        if (dx < best) { best = dx; bl = 2*lp; }
        if (dy < best) { best = dy; bl = 2*lp + 1; }
    }
    labels[n] = bl;
    atomicAdd(&hist[bl], 1);
    __syncthreads();
    if (tid < N_CODEBOOKS) atomicAdd(&cnt[tid], hist[tid]);
}

// ---------------------------------------------------------------- scan (1 wave)
__global__ void pq_scan(const int* __restrict__ cnt, int* __restrict__ off, int* __restrict__ cursor)
{
    int tid = threadIdx.x;
    int v = cnt[tid];
    int inc = v;
#pragma unroll
    for (int sft = 1; sft < 64; sft <<= 1) {
        int o = __shfl_up(inc, sft, 64);
        if (tid >= sft) inc += o;
    }
    int exc = inc - v;
    off[tid] = exc;
    cursor[tid] = exc;
    if (tid == 63) off[64] = inc;
}

// ---------------------------------------------------------------- counting-sort scatter + permute-gather
__global__ __launch_bounds__(256) void pq_scatter(
    const float* __restrict__ x, const int* __restrict__ labels,
    int* __restrict__ cursor, unsigned int* __restrict__ perm,
    float* __restrict__ xg)
{
    __shared__ int lcnt[N_CODEBOOKS];
    __shared__ int lbase[N_CODEBOOKS];
    int tid = threadIdx.x;
    if (tid < N_CODEBOOKS) lcnt[tid] = 0;
    __syncthreads();
    int base = blockIdx.x * 1024;
    int lv[4], slot[4];
#pragma unroll
    for (int i = 0; i < 4; i++) {
        int n = base + i * 256 + tid;
        int l = labels[n];
        lv[i] = l;
        slot[i] = atomicAdd(&lcnt[l], 1);
    }
    __syncthreads();
    if (tid < N_CODEBOOKS) lbase[tid] = atomicAdd(&cursor[tid], lcnt[tid]);
    __syncthreads();
#pragma unroll
    for (int i = 0; i < 4; i++) {
        int n = base + i * 256 + tid;
        int dst = lbase[lv[i]] + slot[i];
        perm[dst] = ((unsigned)n << 6) | (unsigned)lv[i];
#pragma unroll
        for (int s = 0; s < N_SUB; s++) {
            float v[D_SUB];
#pragma unroll
            for (int d = 0; d < D_SUB; d++)
                v[d] = x[(size_t)(s * D_SUB + d) * N_DATA + n];   // coalesced
            float4* o = (float4*)(xg + (((size_t)s * N_DATA + (size_t)dst) << 4));
            o[0] = make_float4(v[0],  v[1],  v[2],  v[3]);
            o[1] = make_float4(v[4],  v[5],  v[6],  v[7]);
            o[2] = make_float4(v[8],  v[9],  v[10], v[11]);
            o[3] = make_float4(v[12], v[13], v[14], v[15]);
        }
    }
}

// ---------------------------------------------------------------- stage 2: PQ encode v10 (big-ws)
// Structure identical to the verified 252us encode9 (lane = one point, ballot
// multipass for boundary waves, compiler-scheduled unroll-2). ONLY the
// codebook addressing changes: the pair-interleaved cbT row is a contiguous
// stream (128B per k-pair -> 2 x s_load_dwordx16, 2 cache lines) instead of
// 16 scattered dwordx2 at 1KB stride (16 lines). No manual register
// double-buffering (v9's spill disaster). Arithmetic per (point,k) unchanged:
// sequential-d separate mul/add (contract off), dist = (xn - 2*acc) + cn;
// per-component argmin chains (even/odd k), ascending kkp strict <, merged
// with the exact lower-k tie rule -> numpy first-occurrence. NaN-free.
__global__ __launch_bounds__(256, 8) void pq_encode11(
    const float* __restrict__ xg, const float* __restrict__ cbT,
    const float* __restrict__ cnorm_cb, const unsigned int* __restrict__ perm,
    unsigned char* __restrict__ codes)
{
    int tid = threadIdx.x;
    int s   = blockIdx.x & 7;
    int pos = (int)(blockIdx.x >> 3) * 256 + tid;
    unsigned pk = perm[pos];
    int n = (int)(pk >> 6);
    int l = (int)(pk & 63u);

    const float4* xp = (const float4*)(xg + (((size_t)s * N_DATA + (size_t)pos) << 4));
    float4 x0 = xp[0], x1 = xp[1], x2 = xp[2], x3 = xp[3];
    float xs[D_SUB] = { x0.x, x0.y, x0.z, x0.w, x1.x, x1.y, x1.z, x1.w,
                        x2.x, x2.y, x2.z, x2.w, x3.x, x3.y, x3.z, x3.w };

    // xnorm: numpy strided reduction (sequential d, separate mul/add)
    float xn = 0.f;
#pragma unroll
    for (int d = 0; d < D_SUB; d++)
        xn = __fadd_rn(xn, __fmul_rn(xs[d], xs[d]));

    v2f xs2[D_SUB];
#pragma unroll
    for (int d = 0; d < D_SUB; d++) xs2[d] = (v2f){xs[d], xs[d]};
    const v2f xnv  = (v2f){xn, xn};
    const v2f twov = (v2f){2.f, 2.f};

    int bestk = 0;
    bool done = false;
    while (true) {
        unsigned long long todo = __ballot(!done);
        if (!todo) break;
        int src  = (int)(__ffsll((long long)todo) - 1);
        int lcur = __builtin_amdgcn_readlane(l, src);      // uniform label for this pass

        const float* cbs = cbT      + ((size_t)(lcur * N_SUB + s) << 12);  // [kkp][d][2] stream
        const float* cns = cnorm_cb + ((size_t)(lcur * N_SUB + s) << 8);   // uniform

        float bx = 1e30f, by = 1e30f;
        int   kx = 0, ky = 0;
        {
#pragma clang fp contract(off)
#pragma unroll 2
            for (int kkp = 0; kkp < N_CLUSTERS / 2; kkp++) {
                v2f cn2 = *(const v2f*)(cns + (kkp << 1));
                v2f a = (v2f){0.f, 0.f};
#pragma unroll
                for (int d = 0; d < D_SUB; d++) {
                    v2f c = *(const v2f*)(cbs + (kkp << 5) + (d << 1));  // contiguous 128B/kkp
                    a = a + xs2[d] * c;          // v_pk_mul + v_pk_add, exact order
                }
                v2f dd = (xnv - twov * a) + cn2;
                if (dd.x < bx) { bx = dd.x; kx = kkp; }
                if (dd.y < by) { by = dd.y; ky = kkp; }
            }
        }
        // merge even/odd chains: strictly-better or equal-with-lower-k picks odd
        int bk = 2 * kx;
        { int kodd = 2 * ky + 1; if (by < bx || (by == bx && kodd < bk)) bk = kodd; }

        if (!done && l == lcur) { bestk = bk; done = true; }
    }
    codes[((size_t)n << 3) | s] = (unsigned char)bestk;
}

// ---------------------------------------------------------------- stage 2 fallback (small-ws): v8 encode
__global__ __launch_bounds__(256, 8) void pq_encode9(
    const float* __restrict__ xg, const float* __restrict__ cb,
    const float* __restrict__ cnorm_cb, const unsigned int* __restrict__ perm,
    unsigned char* __restrict__ codes)
{
    int tid = threadIdx.x;
    int s   = blockIdx.x & 7;
    int pos = (int)(blockIdx.x >> 3) * 256 + tid;
    unsigned pk = perm[pos];
    int n = (int)(pk >> 6);
    int l = (int)(pk & 63u);

    const float4* xp = (const float4*)(xg + (((size_t)s * N_DATA + (size_t)pos) << 4));
    float4 x0 = xp[0], x1 = xp[1], x2 = xp[2], x3 = xp[3];
    float xs[D_SUB] = { x0.x, x0.y, x0.z, x0.w, x1.x, x1.y, x1.z, x1.w,
                        x2.x, x2.y, x2.z, x2.w, x3.x, x3.y, x3.z, x3.w };

    float xn = 0.f;
#pragma unroll
    for (int d = 0; d < D_SUB; d++)
        xn = __fadd_rn(xn, __fmul_rn(xs[d], xs[d]));

    v2f xs2[D_SUB];
#pragma unroll
    for (int d = 0; d < D_SUB; d++) xs2[d] = (v2f){xs[d], xs[d]};
    const v2f xnv  = (v2f){xn, xn};
    const v2f twov = (v2f){2.f, 2.f};

    int bestk = 0;
    bool done = false;
    while (true) {
        unsigned long long todo = __ballot(!done);
        if (!todo) break;
        int src  = (int)(__ffsll((long long)todo) - 1);
        int lcur = __builtin_amdgcn_readlane(l, src);

        const float* cbs = cb       + ((size_t)(lcur * N_SUB + s) << 12);
        const float* cns = cnorm_cb + ((size_t)(lcur * N_SUB + s) << 8);

        float bx = 1e30f, by = 1e30f;
        int   kx = 0, ky = 0;
        {
#pragma clang fp contract(off)
#pragma unroll 2
            for (int kkp = 0; kkp < N_CLUSTERS / 2; kkp++) {
                v2f cn2 = *(const v2f*)(cns + (kkp << 1));
                v2f a = (v2f){0.f, 0.f};
#pragma unroll
                for (int d = 0; d < D_SUB; d++) {
                    v2f c = *(const v2f*)(cbs + (size_t)(d * N_CLUSTERS) + (kkp << 1));
                    a = a + xs2[d] * c;
                }
                v2f dd = (xnv - twov * a) + cn2;
                if (dd.x < bx) { bx = dd.x; kx = kkp; }
                if (dd.y < by) { by = dd.y; ky = kkp; }
            }
        }
        int bk = 2 * kx;
        { int kodd = 2 * ky + 1; if (by < bx || (by == bx && kodd < bk)) bk = kodd; }

        if (!done && l == lcur) { bestk = bk; done = true; }
    }
    codes[((size_t)n << 3) | s] = (unsigned char)bestk;
}

// ---------------------------------------------------------------- decode (fast): 2 lines per (n,s), from cbT
__global__ __launch_bounds__(256) void pq_decode_fast(
    const float* __restrict__ cbT, const int* __restrict__ labels,
    const unsigned char* __restrict__ codes, float* __restrict__ out)
{
    int s = blockIdx.x & 7;
    int n = (blockIdx.x >> 3) * 256 + threadIdx.x;
    int l = labels[n];
    int k = codes[(size_t)n * N_SUB + s];
    const float* base = cbT + ((size_t)(l * N_SUB + s) << 12) + ((size_t)(k >> 1) << 5) + (k & 1);
    float v[D_SUB];
#pragma unroll
    for (int dd = 0; dd < D_SUB; dd++) v[dd] = base[dd << 1];
#pragma unroll
    for (int dd = 0; dd < D_SUB; dd++)
        out[(size_t)(s * D_SUB + dd) * N_DATA + n] = v[dd];   // coalesced
}

// ---------------------------------------------------------------- decode (fallback): strided column gather
__global__ __launch_bounds__(256) void pq_decode(
    const float* __restrict__ cb, const int* __restrict__ labels,
    const unsigned char* __restrict__ codes, float* __restrict__ out)
{
    int s = blockIdx.x & 7;
    int n = (blockIdx.x >> 3) * 256 + threadIdx.x;
    int l = labels[n];
    int k = codes[(size_t)n * N_SUB + s];
    const float* base = cb + ((size_t)(l * N_SUB + s) * D_SUB) * N_CLUSTERS + k;
#pragma unroll
    for (int dd = 0; dd < D_SUB; dd++)
        out[(size_t)(s * D_SUB + dd) * N_DATA + n] = base[(size_t)dd * N_CLUSTERS];
}

// ---------------------------------------------------------------- launcher
extern "C" void kernel_launch(void* const* d_in, const int* in_sizes, int n_in,
                              void* d_out, int out_size, void* d_ws, size_t ws_size,
                              hipStream_t stream)
{
    (void)in_sizes; (void)n_in; (void)out_size;
    const float* x   = (const float*)d_in[0];
    const float* cb  = (const float*)d_in[1];
    const float* sel = (const float*)d_in[2];
    float* out = (float*)d_out;

    int*   wsi    = (int*)d_ws;
    float* wsf    = (float*)d_ws;
    int*   labels = wsi + WS_LABELS;
    unsigned int* perm = (unsigned int*)(wsi + WS_PERM);
    int*   cnt    = wsi + WS_CNT;
    int*   cursor = wsi + WS_CURSOR;
    int*   off    = wsi + WS_OFF;
    float* cnorm  = wsf + WS_CNORM;
    float* cnsel  = wsf + WS_CNSEL;
    unsigned char* codes = (unsigned char*)(wsi + WS_CODES);

    // pair-interleaved codebook only if the workspace is big enough (~11 MiB)
    bool big = ws_size >= (size_t)(WS_CBT + CBT_WORDS) * 4u;
    float* cbT = big ? (wsf + WS_CBT) : (float*)nullptr;

    // permuted-gathered x (64 MiB) lives in d_out; decode overwrites it fully
    float* xg = out;

    hipLaunchKernelGGL(pq_precompute, dim3(512), dim3(256), 0, stream, cb, sel, cnorm, cnsel, cbT, cnt);
    hipLaunchKernelGGL(pq_labels2, dim3(N_DATA / 256), dim3(256), 0, stream, x, sel, cnsel, labels, cnt);
    hipLaunchKernelGGL(pq_scan, dim3(1), dim3(64), 0, stream, cnt, off, cursor);
    hipLaunchKernelGGL(pq_scatter, dim3(N_DATA / 1024), dim3(256), 0, stream, x, labels, cursor, perm, xg);
    if (big) {
        hipLaunchKernelGGL(pq_encode11, dim3((N_DATA / 256) * N_SUB), dim3(256), 0, stream,
                           xg, cbT, cnorm, perm, codes);
        hipLaunchKernelGGL(pq_decode_fast, dim3((N_DATA / 256) * N_SUB), dim3(256), 0, stream,
                           cbT, labels, codes, out);
    } else {
        hipLaunchKernelGGL(pq_encode9, dim3((N_DATA / 256) * N_SUB), dim3(256), 0, stream,
                           xg, cb, cnorm, perm, codes);
        hipLaunchKernelGGL(pq_decode, dim3((N_DATA / 256) * N_SUB), dim3(256), 0, stream,
                           cb, labels, codes, out);
    }
}